// Round 4
// baseline (522.339 us; speedup 1.0000x reference)
//
#include <hip/hip_runtime.h>
#include <hip/hip_cooperative_groups.h>

namespace cg = cooperative_groups;

// ---------------------------------------------------------------------------
// Token performer block, FP32 I/O, internal bf16 MFMA 16x16x32.
// B=64, T=3136, IN=147, D=64, M=32. Tokens tiled 64/block, 512 threads.
// R8: single cooperative kernel = inline prep + grid.sync + R6 pass1 tile
// loop + grid.sync + R6 pass2 tile loop. Phase bodies byte-identical to the
// verified R6 (315us). Grid sized from the occupancy API so cooperative
// launch always validates; fallback to the 3-kernel R6 path if the
// cooperative launch is rejected.
// ---------------------------------------------------------------------------

typedef __attribute__((ext_vector_type(8))) __bf16 bf16x8;
typedef __attribute__((ext_vector_type(4))) __bf16 bf16x4;
typedef __attribute__((ext_vector_type(4))) float  f32x4;

#define DEV __device__ __forceinline__

constexpr int Bc = 64, Tc = 3136, INDIM = 147, TM = 64;
constexpr int NTILE = 3136;   // 64 b * 49 t-tiles

// ---- workspace layout (bytes) ----
constexpr size_t WS_QP   = 0;                                   // bf16 B*T*32  [t][m]
constexpr size_t WS_ZERO = WS_QP + (size_t)Bc * Tc * 32 * 2;    // fp32 accumulators
constexpr size_t WS_KPS  = WS_ZERO;                             // fp32 B*32
constexpr size_t WS_KPTV = WS_KPS + (size_t)Bc * 32 * 4;        // fp32 B*64*32 [d][m]
constexpr size_t WS_IMG  = WS_KPTV + (size_t)Bc * 64 * 32 * 4;
constexpr int ZCOUNT = Bc * 32 + Bc * 64 * 32;                  // 133120 floats

// ---- weight image element offsets (bf16 elements) ----
constexpr int IMG_W1T   = 0;      // [64][168]  W_proj1^T, K padded 147->160(+8)
constexpr int IMG_WKQVT = 10752;  // [192][72]  W_kqv^T (k 0..63, q 64..127, v 128..191)
constexpr int IMG_WF    = 24576;  // [32][72]   w [m][d]
constexpr int IMG_W2T   = 26880;  // [64][72]
constexpr int IMG_WM1T  = 31488;  // [64][72]
constexpr int IMG_WM2T  = 36096;  // [64][72]

// wave 16x16 tile GEMM: A rows m-major (k contiguous), B rows n-major (k contiguous).
// out element (m0 + (lane>>4)*4 + i, n0 + (lane&15)) = acc[i]
DEV f32x4 gemm_tile(const __bf16* A, int lda, const __bf16* Bm, int ldb,
                    int K, int r, int qd) {
    f32x4 acc = {0.f, 0.f, 0.f, 0.f};
    const __bf16* ap = A + r * lda + qd * 8;
    const __bf16* bp = Bm + r * ldb + qd * 8;
#pragma unroll
    for (int k = 0; k < 160; k += 32) {
        if (k >= K) break;
        bf16x8 av = *(const bf16x8*)(ap + k);
        bf16x8 bv = *(const bf16x8*)(bp + k);
        acc = __builtin_amdgcn_mfma_f32_16x16x32_bf16(av, bv, acc, 0, 0, 0);
    }
    return acc;
}

// ===========================================================================
// Shared phase bodies (device-inline). LDS layouts identical to R6.
// ===========================================================================

// prep work distributed over (gtid, n) threads
DEV void prep_body(int gtid, int n,
                   const float* W1, const float* Wkqv, const float* wm,
                   const float* W2, const float* Wm1, const float* Wm2,
                   char* ws) {
    float* z = (float*)(ws + WS_ZERO);
    for (int i = gtid; i < ZCOUNT; i += n) z[i] = 0.f;
    __bf16* wimg = (__bf16*)(ws + WS_IMG);
    for (int i = gtid; i < 64 * 168; i += n) {   // W1T [d][k]
        int d = i / 168, k = i - d * 168;
        wimg[IMG_W1T + i] = (k < 147) ? (__bf16)W1[k * 64 + d] : (__bf16)0.f;
    }
    for (int i = gtid; i < 192 * 72; i += n) {   // WkqvT [c][k]
        int c = i / 72, k = i - c * 72;
        wimg[IMG_WKQVT + i] = (k < 64) ? (__bf16)Wkqv[k * 192 + c] : (__bf16)0.f;
    }
    for (int i = gtid; i < 32 * 72; i += n) {    // wF [m][d]
        int m = i / 72, k = i - m * 72;
        wimg[IMG_WF + i] = (k < 64) ? (__bf16)wm[m * 64 + k] : (__bf16)0.f;
    }
    for (int i = gtid; i < 64 * 72; i += n) {
        int c = i / 72, k = i - c * 72;
        wimg[IMG_W2T + i] = (k < 64) ? (__bf16)W2[k * 64 + c] : (__bf16)0.f;
    }
    for (int i = gtid; i < 64 * 72; i += n) {
        int c = i / 72, k = i - c * 72;
        wimg[IMG_WM1T + i] = (k < 64) ? (__bf16)Wm1[k * 64 + c] : (__bf16)0.f;
    }
    for (int i = gtid; i < 64 * 72; i += n) {
        int c = i / 72, k = i - c * 72;
        wimg[IMG_WM2T + i] = (k < 64) ? (__bf16)Wm2[k * 64 + c] : (__bf16)0.f;
    }
}

// ---------------------------------------------------------------------------
// pass1 tile body. LDS (40576 B): layout identical to R6.
DEV void pass1_body(char* smem, int tid, int wv, int r, int qd, int b, int t0,
                    const float* x, const float* b1, const float* bkqv,
                    const float* g1, const float* be1, char* ws,
                    float* vout) {
    __bf16* sXT  = (__bf16*)(smem);
    __bf16* sK   = (__bf16*)(smem);
    __bf16* sQ   = (__bf16*)(smem + 9216);
    __bf16* sH   = (__bf16*)(smem + 21504);
    __bf16* sKPT = (__bf16*)(smem + 21504);
    __bf16* sVT  = (__bf16*)(smem + 30720);
    float*  sXDK = (float*)(smem + 39936);
    float*  sXDQ = (float*)(smem + 40192);
    float*  sKPS = (float*)(smem + 40448);
    const __bf16* img = (const __bf16*)(ws + WS_IMG);

    // ---- P0: stage x tile fp32->bf16, float4 loads ----
    {
        const float* xrow = x + (size_t)(b * Tc + t0) * INDIM;
        const f32x4* xp4 = (const f32x4*)xrow;                  // 2352 float4s
        for (int i4 = tid; i4 < 2352; i4 += 512) {
            f32x4 xv = xp4[i4];
            int g = i4 << 2;
            int t = g / 147;
            int k = g - t * 147;
#pragma unroll
            for (int j = 0; j < 4; j++) {
                sXT[t * 168 + k] = (__bf16)xv[j];
                k++;
                if (k == 147) { k = 0; t++; }
            }
        }
        for (int i = tid; i < TM * 21; i += 512) {
            int t = i / 21, k = 147 + (i - t * 21);
            sXT[t * 168 + k] = (__bf16)0.f;
        }
    }
    __syncthreads();

    // ---- P1: h = x @ W1 + b1 ----
    for (int id = wv; id < 16; id += 8) {
        int m0 = (id & 3) * 16, n0 = (id >> 2) * 16;
        f32x4 acc = gemm_tile(sXT + m0 * 168, 168, img + IMG_W1T + n0 * 168, 168, 160, r, qd);
        int d = n0 + r;
        float bias = b1[d];
#pragma unroll
        for (int i = 0; i < 4; i++)
            sH[(m0 + qd * 4 + i) * 72 + d] = (__bf16)(acc[i] + bias);
    }
    __syncthreads();

    // ---- P2: LN1 in place ----
    {
        int t = tid >> 3, p = tid & 7;
        __bf16* hp = sH + t * 72 + p * 8;
        bf16x8 hv = *(const bf16x8*)hp;
        float v[8], s1 = 0.f, s2 = 0.f;
#pragma unroll
        for (int i = 0; i < 8; i++) { v[i] = (float)hv[i]; s1 += v[i]; s2 += v[i] * v[i]; }
#pragma unroll
        for (int m = 1; m < 8; m <<= 1) { s1 += __shfl_xor(s1, m); s2 += __shfl_xor(s2, m); }
        float mu = s1 * (1.f / 64.f), var = s2 * (1.f / 64.f) - mu * mu;
        float rstd = rsqrtf(var + 1e-5f);
        bf16x8 o;
#pragma unroll
        for (int i = 0; i < 8; i++) {
            int d = p * 8 + i;
            o[i] = (__bf16)((v[i] - mu) * rstd * g1[d] + be1[d]);
        }
        *(bf16x8*)hp = o;
    }
    __syncthreads();

    // ---- P3: k, q, v = hn @ Wk/Wq/Wv + bias (48 tiles) ----
    for (int id = wv; id < 48; id += 8) {
        int which = id >> 4, tl = id & 15;
        int m0 = (tl & 3) * 16, n0 = (tl >> 2) * 16;
        const __bf16* Bm = img + IMG_WKQVT + which * 64 * 72 + n0 * 72;
        f32x4 acc = gemm_tile(sH + m0 * 72, 72, Bm, 72, 64, r, qd);
        int nn = n0 + r;
        float bias = bkqv[which * 64 + nn];
        if (which == 0) {
#pragma unroll
            for (int i = 0; i < 4; i++)
                sK[(m0 + qd * 4 + i) * 72 + nn] = (__bf16)(acc[i] + bias);
        } else if (which == 1) {
#pragma unroll
            for (int i = 0; i < 4; i++)
                sQ[(m0 + qd * 4 + i) * 72 + nn] = (__bf16)(acc[i] + bias);
        } else {
#pragma unroll
            for (int i = 0; i < 4; i++)
                sVT[nn * 72 + (m0 + qd * 4 + i)] = (__bf16)(acc[i] + bias);
        }
    }
    __syncthreads();

    // ---- P4: |k|^2/2, |q|^2/2; v park to d_out tile; zero sKPS ----
    {
        int t = tid >> 3, p = tid & 7;
        bf16x8 kv = *(const bf16x8*)(sK + t * 72 + p * 8);
        bf16x8 qv = *(const bf16x8*)(sQ + t * 72 + p * 8);
        float sk = 0.f, sq = 0.f;
#pragma unroll
        for (int i = 0; i < 8; i++) {
            float a = (float)kv[i]; sk += a * a;
            float c = (float)qv[i]; sq += c * c;
        }
#pragma unroll
        for (int m = 1; m < 8; m <<= 1) { sk += __shfl_xor(sk, m); sq += __shfl_xor(sq, m); }
        if (p == 0) { sXDK[t] = 0.5f * sk; sXDQ[t] = 0.5f * sq; }
        if (tid < 32) sKPS[tid] = 0.f;
        __bf16* vg = (__bf16*)(vout + (size_t)(b * Tc + t0) * 64);
        int dd = tid >> 3, tt0 = (tid & 7) * 8;
        *(bf16x8*)(vg + dd * 64 + tt0) = *(const bf16x8*)(sVT + dd * 72 + tt0);
    }
    __syncthreads();

    // ---- P5: kp (waves 0-3 -> sKPT + kps) ; qp (waves 4-7 -> global bf16) ----
    {
        const int wv4 = wv & 3;
        const bool isq = (wv >= 4);
        const __bf16* Aop = isq ? sQ : sK;
        const float* xd = isq ? sXDQ : sXDK;
        __bf16* qg = (__bf16*)(ws + WS_QP) + (size_t)(b * Tc + t0) * 32;
#pragma unroll
        for (int nb = 0; nb < 2; nb++) {
            int m0 = wv4 * 16, n0 = nb * 16;
            f32x4 acc = gemm_tile(Aop + m0 * 72, 72, img + IMG_WF + n0 * 72, 72, 64, r, qd);
            int m = n0 + r;
            if (!isq) {
                float loc = 0.f;
#pragma unroll
                for (int i = 0; i < 4; i++) {
                    int t = m0 + qd * 4 + i;
                    float val = __expf(acc[i] - xd[t]) * 0.17677669529663687f;
                    sKPT[m * 72 + t] = (__bf16)val;
                    loc += val;
                }
                loc += __shfl_xor(loc, 16);
                loc += __shfl_xor(loc, 32);
                if (qd == 0) atomicAdd(&sKPS[m], loc);
            } else {
#pragma unroll
                for (int i = 0; i < 4; i++) {
                    int t = m0 + qd * 4 + i;
                    float val = __expf(acc[i] - xd[t]) * 0.17677669529663687f;
                    qg[t * 32 + m] = (__bf16)val;
                }
            }
        }
    }
    __syncthreads();

    // ---- P6: kptv partials -> global atomics; kps -> global ----
    {
        float* kptv = (float*)(ws + WS_KPTV) + b * 2048;
        int mb = wv & 1, nb = wv >> 1;
        f32x4 acc = gemm_tile(sKPT + mb * 16 * 72, 72, sVT + nb * 16 * 72, 72, 64, r, qd);
#pragma unroll
        for (int i = 0; i < 4; i++) {
            int m = mb * 16 + qd * 4 + i, d = nb * 16 + r;
            atomicAdd(&kptv[d * 32 + m], acc[i]);
        }
        float* kps = (float*)(ws + WS_KPS) + b * 32;
        if (tid < 32) atomicAdd(&kps[tid], sKPS[tid]);
    }
}

// ---------------------------------------------------------------------------
// pass2 tile body. LDS (38272 B): layout identical to R6.
DEV void pass2_body(char* smem, int tid, int wv, int r, int qd, int b, int t0,
                    const float* b2, const float* g2, const float* be2,
                    const float* bm1, const float* bm2, char* ws,
                    float* out) {
    __bf16* sKPTV = (__bf16*)(smem);
    __bf16* sQPL  = (__bf16*)(smem + 5120);
    __bf16* sGL   = (__bf16*)(smem);
    __bf16* sVLT  = (__bf16*)(smem + 10240);
    __bf16* sYN   = (__bf16*)(smem + 10240);
    __bf16* sYA   = (__bf16*)(smem + 19456);
    __bf16* sYL   = (__bf16*)(smem + 28672);
    float*  sKPS  = (float*)(smem + 37888);
    float*  sDL   = (float*)(smem + 38016);
    const __bf16* img = (const __bf16*)(ws + WS_IMG);

    // ---- P0: load kptv (float4/thread), kps, qp (bf16x8), v (bf16x8) ----
    {
        const f32x4* kp4 = (const f32x4*)((const float*)(ws + WS_KPTV) + b * 2048);
        f32x4 kv = kp4[tid];
        int d = tid >> 3, m0 = (tid & 7) * 4;
        bf16x4 kb;
#pragma unroll
        for (int j = 0; j < 4; j++) kb[j] = (__bf16)kv[j];
        *(bf16x4*)(sKPTV + d * 40 + m0) = kb;
        if (tid < 32) sKPS[tid] = ((const float*)(ws + WS_KPS))[b * 32 + tid];
        if (tid < 256) {
            const bf16x8* qp8 = (const bf16x8*)((const __bf16*)(ws + WS_QP) +
                                                (size_t)(b * Tc + t0) * 32);
            bf16x8 q8 = qp8[tid];
            int t = tid >> 2, mm = (tid & 3) * 8;
            *(bf16x8*)(sQPL + t * 40 + mm) = q8;
        }
        const __bf16* vg = (const __bf16*)(out + (size_t)(b * Tc + t0) * 64);
        int dd = tid >> 3, tt0 = (tid & 7) * 8;
        *(bf16x8*)(sVLT + dd * 72 + tt0) = *(const bf16x8*)(vg + dd * 64 + tt0);
    }
    __syncthreads();

    // ---- P1: D = qp . kp_sum + eps ----
    {
        int t = tid >> 3, p = tid & 7;
        float s = 0.f;
#pragma unroll
        for (int j = 0; j < 4; j++) {
            int m = p * 4 + j;
            s += (float)sQPL[t * 40 + m] * sKPS[m];
        }
#pragma unroll
        for (int m = 1; m < 8; m <<= 1) s += __shfl_xor(s, m);
        if (p == 0) sDL[t] = s + 1e-8f;
    }
    __syncthreads();

    // ---- P2: ya = (qp @ kptv^T) / D ----
    for (int id = wv; id < 16; id += 8) {
        int m0 = (id & 3) * 16, n0 = (id >> 2) * 16;
        f32x4 acc = gemm_tile(sQPL + m0 * 40, 40, sKPTV + n0 * 40, 40, 32, r, qd);
        int d = n0 + r;
#pragma unroll
        for (int i = 0; i < 4; i++) {
            int t = m0 + qd * 4 + i;
            sYA[t * 72 + d] = (__bf16)(acc[i] / sDL[t]);
        }
    }
    __syncthreads();

    // ---- P3: y = v + ya @ W_proj2 + b2 ----
    for (int id = wv; id < 16; id += 8) {
        int m0 = (id & 3) * 16, n0 = (id >> 2) * 16;
        f32x4 acc = gemm_tile(sYA + m0 * 72, 72, img + IMG_W2T + n0 * 72, 72, 64, r, qd);
        int d = n0 + r;
        float bias = b2[d];
#pragma unroll
        for (int i = 0; i < 4; i++) {
            int t = m0 + qd * 4 + i;
            sYL[t * 72 + d] = (__bf16)(acc[i] + bias + (float)sVLT[d * 72 + t]);
        }
    }
    __syncthreads();

    // ---- P4: LN2 -> yn ----
    {
        int t = tid >> 3, p = tid & 7;
        bf16x8 yv = *(const bf16x8*)(sYL + t * 72 + p * 8);
        float v[8], s1 = 0.f, s2 = 0.f;
#pragma unroll
        for (int i = 0; i < 8; i++) { v[i] = (float)yv[i]; s1 += v[i]; s2 += v[i] * v[i]; }
#pragma unroll
        for (int m = 1; m < 8; m <<= 1) { s1 += __shfl_xor(s1, m); s2 += __shfl_xor(s2, m); }
        float mu = s1 * (1.f / 64.f), var = s2 * (1.f / 64.f) - mu * mu;
        float rstd = rsqrtf(var + 1e-5f);
        bf16x8 o;
#pragma unroll
        for (int i = 0; i < 8; i++) {
            int d = p * 8 + i;
            o[i] = (__bf16)((v[i] - mu) * rstd * g2[d] + be2[d]);
        }
        *(bf16x8*)(sYN + t * 72 + p * 8) = o;
    }
    __syncthreads();

    // ---- P5: gl = gelu(yn @ W_m1 + bm1) ----
    for (int id = wv; id < 16; id += 8) {
        int m0 = (id & 3) * 16, n0 = (id >> 2) * 16;
        f32x4 acc = gemm_tile(sYN + m0 * 72, 72, img + IMG_WM1T + n0 * 72, 72, 64, r, qd);
        int d = n0 + r;
        float bias = bm1[d];
#pragma unroll
        for (int i = 0; i < 4; i++) {
            int t = m0 + qd * 4 + i;
            float z = acc[i] + bias;
            sGL[t * 72 + d] = (__bf16)(0.5f * z * (1.f + erff(z * 0.7071067811865475f)));
        }
    }
    __syncthreads();

    // ---- P6: out = y + (gl @ W_m2 + bm2), fp32 store ----
    {
        float* og = out + (size_t)(b * Tc + t0) * 64;
        for (int id = wv; id < 16; id += 8) {
            int m0 = (id & 3) * 16, n0 = (id >> 2) * 16;
            f32x4 acc = gemm_tile(sGL + m0 * 72, 72, img + IMG_WM2T + n0 * 72, 72, 64, r, qd);
            int d = n0 + r;
            float bias = bm2[d];
#pragma unroll
            for (int i = 0; i < 4; i++) {
                int t = m0 + qd * 4 + i;
                og[t * 64 + d] = acc[i] + bias + (float)sYL[t * 72 + d];
            }
        }
    }
}

// ===========================================================================
// Fused cooperative kernel
// ===========================================================================
__global__ __launch_bounds__(512, 8) void fused_kernel(
    const float* __restrict__ x,
    const float* __restrict__ W1,  const float* __restrict__ b1,
    const float* __restrict__ Wkqv, const float* __restrict__ bkqv,
    const float* __restrict__ W2,  const float* __restrict__ b2,
    const float* __restrict__ g1,  const float* __restrict__ be1,
    const float* __restrict__ g2,  const float* __restrict__ be2,
    const float* __restrict__ Wm1, const float* __restrict__ bm1,
    const float* __restrict__ Wm2, const float* __restrict__ bm2,
    const float* __restrict__ wm,
    char* __restrict__ ws, float* __restrict__ out) {
    __shared__ __align__(16) char smem[40576];
    const int tid = threadIdx.x;
    const int wv = tid >> 6, lane = tid & 63, r = lane & 15, qd = lane >> 4;

    // ---- phase A: prep ----
    prep_body(blockIdx.x * 512 + tid, gridDim.x * 512,
              W1, Wkqv, wm, W2, Wm1, Wm2, ws);
    cg::this_grid().sync();

    // ---- phase B: pass1 tiles ----
    for (int tile = blockIdx.x; tile < NTILE; tile += gridDim.x) {
        __syncthreads();
        pass1_body(smem, tid, wv, r, qd, tile & 63, (tile >> 6) << 6,
                   x, b1, bkqv, g1, be1, ws, out);
    }
    cg::this_grid().sync();

    // ---- phase C: pass2 tiles ----
    for (int tile = blockIdx.x; tile < NTILE; tile += gridDim.x) {
        __syncthreads();
        pass2_body(smem, tid, wv, r, qd, tile & 63, (tile >> 6) << 6,
                   b2, g2, be2, bm1, bm2, ws, out);
    }
}

// ===========================================================================
// Fallback 3-kernel path (verified R6 structure), used only if the
// cooperative launch is rejected by the runtime.
// ===========================================================================
__global__ void prep_kernel(const float* __restrict__ W1, const float* __restrict__ Wkqv,
                            const float* __restrict__ wm, const float* __restrict__ W2,
                            const float* __restrict__ Wm1, const float* __restrict__ Wm2,
                            char* __restrict__ ws) {
    prep_body(blockIdx.x * blockDim.x + threadIdx.x, gridDim.x * blockDim.x,
              W1, Wkqv, wm, W2, Wm1, Wm2, ws);
}

__global__ __launch_bounds__(512, 8) void pass1_kernel(
    const float* __restrict__ x, const float* __restrict__ b1,
    const float* __restrict__ bkqv, const float* __restrict__ g1,
    const float* __restrict__ be1, char* __restrict__ ws,
    float* __restrict__ vout) {
    __shared__ __align__(16) char smem[40576];
    const int tid = threadIdx.x;
    const int wv = tid >> 6, lane = tid & 63, r = lane & 15, qd = lane >> 4;
    pass1_body(smem, tid, wv, r, qd, blockIdx.x & 63, (blockIdx.x >> 6) << 6,
               x, b1, bkqv, g1, be1, ws, vout);
}

__global__ __launch_bounds__(512, 8) void pass2_kernel(
    const float* __restrict__ b2, const float* __restrict__ g2,
    const float* __restrict__ be2, const float* __restrict__ bm1,
    const float* __restrict__ bm2, char* __restrict__ ws,
    float* __restrict__ out) {
    __shared__ __align__(16) char smem[38272];
    const int tid = threadIdx.x;
    const int wv = tid >> 6, lane = tid & 63, r = lane & 15, qd = lane >> 4;
    pass2_body(smem, tid, wv, r, qd, blockIdx.x & 63, (blockIdx.x >> 6) << 6,
               b2, g2, be2, bm1, bm2, ws, out);
}

// ---------------------------------------------------------------------------
extern "C" void kernel_launch(void* const* d_in, const int* in_sizes, int n_in,
                              void* d_out, int out_size, void* d_ws, size_t ws_size,
                              hipStream_t stream) {
    (void)in_sizes; (void)n_in; (void)out_size; (void)ws_size;
    const float* x    = (const float*)d_in[0];
    const float* W1   = (const float*)d_in[1];
    const float* b1   = (const float*)d_in[2];
    const float* Wkqv = (const float*)d_in[3];
    const float* bkqv = (const float*)d_in[4];
    const float* W2   = (const float*)d_in[5];
    const float* b2   = (const float*)d_in[6];
    const float* g1   = (const float*)d_in[7];
    const float* be1  = (const float*)d_in[8];
    const float* g2   = (const float*)d_in[9];
    const float* be2  = (const float*)d_in[10];
    const float* Wm1  = (const float*)d_in[11];
    const float* bm1  = (const float*)d_in[12];
    const float* Wm2  = (const float*)d_in[13];
    const float* bm2  = (const float*)d_in[14];
    const float* wm   = (const float*)d_in[15];
    char* ws = (char*)d_ws;
    float* outp = (float*)d_out;

    // Grid sized so the cooperative launch always validates: blocks/CU from
    // the occupancy API (LDS 40960B -> expect 3-4 blocks/CU on MI355X).
    static int coop_grid = 0;
    if (coop_grid == 0) {
        int maxb = 0;
        if (hipOccupancyMaxActiveBlocksPerMultiprocessor(&maxb, fused_kernel, 512, 0)
                != hipSuccess || maxb < 1)
            maxb = 1;
        long g = (long)maxb * 256;
        if (g > NTILE) g = NTILE;
        coop_grid = (int)g;
    }

    void* args[] = {(void*)&x, (void*)&W1, (void*)&b1, (void*)&Wkqv, (void*)&bkqv,
                    (void*)&W2, (void*)&b2, (void*)&g1, (void*)&be1, (void*)&g2,
                    (void*)&be2, (void*)&Wm1, (void*)&bm1, (void*)&Wm2, (void*)&bm2,
                    (void*)&wm, (void*)&ws, (void*)&outp};
    hipError_t e = hipLaunchCooperativeKernel((void*)fused_kernel,
                                              dim3(coop_grid), dim3(512),
                                              args, 0, stream);
    if (e != hipSuccess) {
        (void)hipGetLastError();   // clear sticky error, fall back to 3-kernel path
        hipLaunchKernelGGL(prep_kernel, dim3(128), dim3(256), 0, stream,
                           W1, Wkqv, wm, W2, Wm1, Wm2, ws);
        hipLaunchKernelGGL(pass1_kernel, dim3(3136), dim3(512), 0, stream,
                           x, b1, bkqv, g1, be1, ws, outp);
        hipLaunchKernelGGL(pass2_kernel, dim3(3136), dim3(512), 0, stream,
                           b2, g2, be2, bm1, bm2, ws, outp);
    }
}

// Round 8
// 315.605 us; speedup vs baseline: 1.6550x; 1.6550x over previous
//
#include <hip/hip_runtime.h>

// ---------------------------------------------------------------------------
// Token performer block, FP32 I/O, internal bf16 MFMA 16x16x32.
// B=64, T=3136, IN=147, D=64, M=32. Tokens tiled 64/block, 512 threads.
// R11 (resubmit; previous round died on container infra, kernel unmeasured):
// = R6 (verified 315us) with pass1 LDS cut 40576 -> 38912 B to unlock
// 4 blocks/CU (was 3: 40960B rounds against the exact-160KiB boundary):
//   - sXT inner stride 168 -> 160 (K padded only to 160; weight image in
//     global keeps stride 168; saves 1024 B)
//   - sXDK/sXDQ/sKPS stat arrays moved into the dead sXT tail @18432
//     (saves 640 B)
// All phase arithmetic, pass2, prep byte-identical to R6.
// ---------------------------------------------------------------------------

typedef __attribute__((ext_vector_type(8))) __bf16 bf16x8;
typedef __attribute__((ext_vector_type(4))) __bf16 bf16x4;
typedef __attribute__((ext_vector_type(4))) float  f32x4;

#define DEV __device__ __forceinline__

constexpr int Bc = 64, Tc = 3136, INDIM = 147, TM = 64;

// ---- workspace layout (bytes) ----
constexpr size_t WS_QP   = 0;                                   // bf16 B*T*32  [t][m]
constexpr size_t WS_ZERO = WS_QP + (size_t)Bc * Tc * 32 * 2;    // fp32 accumulators
constexpr size_t WS_KPS  = WS_ZERO;                             // fp32 B*32
constexpr size_t WS_KPTV = WS_KPS + (size_t)Bc * 32 * 4;        // fp32 B*64*32 [d][m]
constexpr size_t WS_IMG  = WS_KPTV + (size_t)Bc * 64 * 32 * 4;
constexpr int ZCOUNT = Bc * 32 + Bc * 64 * 32;                  // 133120 floats

// ---- weight image element offsets (bf16 elements) ----
constexpr int IMG_W1T   = 0;      // [64][168]  W_proj1^T, K padded 147->160(+8)
constexpr int IMG_WKQVT = 10752;  // [192][72]  W_kqv^T (k 0..63, q 64..127, v 128..191)
constexpr int IMG_WF    = 24576;  // [32][72]   w [m][d]
constexpr int IMG_W2T   = 26880;  // [64][72]
constexpr int IMG_WM1T  = 31488;  // [64][72]
constexpr int IMG_WM2T  = 36096;  // [64][72]

// wave 16x16 tile GEMM: A rows m-major (k contiguous), B rows n-major (k contiguous).
// out element (m0 + (lane>>4)*4 + i, n0 + (lane&15)) = acc[i]
DEV f32x4 gemm_tile(const __bf16* A, int lda, const __bf16* Bm, int ldb,
                    int K, int r, int qd) {
    f32x4 acc = {0.f, 0.f, 0.f, 0.f};
    const __bf16* ap = A + r * lda + qd * 8;
    const __bf16* bp = Bm + r * ldb + qd * 8;
#pragma unroll
    for (int k = 0; k < 160; k += 32) {
        if (k >= K) break;
        bf16x8 av = *(const bf16x8*)(ap + k);
        bf16x8 bv = *(const bf16x8*)(bp + k);
        acc = __builtin_amdgcn_mfma_f32_16x16x32_bf16(av, bv, acc, 0, 0, 0);
    }
    return acc;
}

// ---------------------------------------------------------------------------
__global__ void prep_kernel(const float* __restrict__ W1, const float* __restrict__ Wkqv,
                            const float* __restrict__ wm, const float* __restrict__ W2,
                            const float* __restrict__ Wm1, const float* __restrict__ Wm2,
                            char* __restrict__ ws) {
    const int tid = blockIdx.x * blockDim.x + threadIdx.x;
    const int n = gridDim.x * blockDim.x;
    float* z = (float*)(ws + WS_ZERO);
    for (int i = tid; i < ZCOUNT; i += n) z[i] = 0.f;
    __bf16* img = (__bf16*)(ws + WS_IMG);
    for (int i = tid; i < 64 * 168; i += n) {   // W1T [d][k]
        int d = i / 168, k = i - d * 168;
        img[IMG_W1T + i] = (k < 147) ? (__bf16)W1[k * 64 + d] : (__bf16)0.f;
    }
    for (int i = tid; i < 192 * 72; i += n) {   // WkqvT [c][k]
        int c = i / 72, k = i - c * 72;
        img[IMG_WKQVT + i] = (k < 64) ? (__bf16)Wkqv[k * 192 + c] : (__bf16)0.f;
    }
    for (int i = tid; i < 32 * 72; i += n) {    // wF [m][d]
        int m = i / 72, k = i - m * 72;
        img[IMG_WF + i] = (k < 64) ? (__bf16)wm[m * 64 + k] : (__bf16)0.f;
    }
    for (int i = tid; i < 64 * 72; i += n) {
        int c = i / 72, k = i - c * 72;
        img[IMG_W2T + i] = (k < 64) ? (__bf16)W2[k * 64 + c] : (__bf16)0.f;
    }
    for (int i = tid; i < 64 * 72; i += n) {
        int c = i / 72, k = i - c * 72;
        img[IMG_WM1T + i] = (k < 64) ? (__bf16)Wm1[k * 64 + c] : (__bf16)0.f;
    }
    for (int i = tid; i < 64 * 72; i += n) {
        int c = i / 72, k = i - c * 72;
        img[IMG_WM2T + i] = (k < 64) ? (__bf16)Wm2[k * 64 + c] : (__bf16)0.f;
    }
}

// ---------------------------------------------------------------------------
// pass1 LDS (38912 B):
//   region A @0     [20480): sXT [64][160]   (P0w, P1r)
//                            then sK@0 [64][72] (P3w, P4/P5r), sQ@9216 (same)
//                            stats in dead sXT tail:
//                              sXDK @18432 f32[64], sXDQ @18688 f32[64],
//                              sKPS @18944 f32[32]   (P4w, P5r/atomic, P6r)
//   region B @20480 [9216):  sH [64][72]     (P1w, P2rw, P3r)
//                            then sKPT@20480 [32][72] (P5w, P6r)
//   sVT @29696 [9216): [64 d][72 t]          (P3w, P4r, P6r)
__global__ __launch_bounds__(512, 8) void pass1_kernel(
    const float* __restrict__ x, const float* __restrict__ b1,
    const float* __restrict__ bkqv, const float* __restrict__ g1,
    const float* __restrict__ be1, char* __restrict__ ws,
    float* __restrict__ vout) {
    __shared__ __align__(16) char smem[38912];
    __bf16* sXT  = (__bf16*)(smem);
    __bf16* sK   = (__bf16*)(smem);
    __bf16* sQ   = (__bf16*)(smem + 9216);
    float*  sXDK = (float*)(smem + 18432);
    float*  sXDQ = (float*)(smem + 18688);
    float*  sKPS = (float*)(smem + 18944);
    __bf16* sH   = (__bf16*)(smem + 20480);
    __bf16* sKPT = (__bf16*)(smem + 20480);
    __bf16* sVT  = (__bf16*)(smem + 29696);

    const int tid = threadIdx.x;
    const int wv = tid >> 6, lane = tid & 63, r = lane & 15, qd = lane >> 4;
    const int b = blockIdx.x & 63;
    const int t0 = (blockIdx.x >> 6) << 6;
    const __bf16* img = (const __bf16*)(ws + WS_IMG);

    // ---- P0: stage x tile fp32->bf16, float4 loads (stride 160 in LDS) ----
    {
        const float* xrow = x + (size_t)(b * Tc + t0) * INDIM;
        const f32x4* xp4 = (const f32x4*)xrow;                  // 2352 float4s
        for (int i4 = tid; i4 < 2352; i4 += 512) {
            f32x4 xv = xp4[i4];
            int g = i4 << 2;
            int t = g / 147;
            int k = g - t * 147;
#pragma unroll
            for (int j = 0; j < 4; j++) {
                sXT[t * 160 + k] = (__bf16)xv[j];
                k++;
                if (k == 147) { k = 0; t++; }
            }
        }
        for (int i = tid; i < TM * 13; i += 512) {
            int t = i / 13, k = 147 + (i - t * 13);
            sXT[t * 160 + k] = (__bf16)0.f;
        }
    }
    __syncthreads();

    // ---- P1: h = x @ W1 + b1 (A lda=160; B image stride 168 unchanged) ----
    for (int id = wv; id < 16; id += 8) {
        int m0 = (id & 3) * 16, n0 = (id >> 2) * 16;
        f32x4 acc = gemm_tile(sXT + m0 * 160, 160, img + IMG_W1T + n0 * 168, 168, 160, r, qd);
        int d = n0 + r;
        float bias = b1[d];
#pragma unroll
        for (int i = 0; i < 4; i++)
            sH[(m0 + qd * 4 + i) * 72 + d] = (__bf16)(acc[i] + bias);
    }
    __syncthreads();

    // ---- P2: LN1 in place ----
    {
        int t = tid >> 3, p = tid & 7;
        __bf16* hp = sH + t * 72 + p * 8;
        bf16x8 hv = *(const bf16x8*)hp;
        float v[8], s1 = 0.f, s2 = 0.f;
#pragma unroll
        for (int i = 0; i < 8; i++) { v[i] = (float)hv[i]; s1 += v[i]; s2 += v[i] * v[i]; }
#pragma unroll
        for (int m = 1; m < 8; m <<= 1) { s1 += __shfl_xor(s1, m); s2 += __shfl_xor(s2, m); }
        float mu = s1 * (1.f / 64.f), var = s2 * (1.f / 64.f) - mu * mu;
        float rstd = rsqrtf(var + 1e-5f);
        bf16x8 o;
#pragma unroll
        for (int i = 0; i < 8; i++) {
            int d = p * 8 + i;
            o[i] = (__bf16)((v[i] - mu) * rstd * g1[d] + be1[d]);
        }
        *(bf16x8*)hp = o;
    }
    __syncthreads();

    // ---- P3: k, q, v = hn @ Wk/Wq/Wv + bias (48 tiles; sK/sQ overwrite sXT) ----
    for (int id = wv; id < 48; id += 8) {
        int which = id >> 4, tl = id & 15;
        int m0 = (tl & 3) * 16, n0 = (tl >> 2) * 16;
        const __bf16* Bm = img + IMG_WKQVT + which * 64 * 72 + n0 * 72;
        f32x4 acc = gemm_tile(sH + m0 * 72, 72, Bm, 72, 64, r, qd);
        int nn = n0 + r;
        float bias = bkqv[which * 64 + nn];
        if (which == 0) {
#pragma unroll
            for (int i = 0; i < 4; i++)
                sK[(m0 + qd * 4 + i) * 72 + nn] = (__bf16)(acc[i] + bias);
        } else if (which == 1) {
#pragma unroll
            for (int i = 0; i < 4; i++)
                sQ[(m0 + qd * 4 + i) * 72 + nn] = (__bf16)(acc[i] + bias);
        } else {
#pragma unroll
            for (int i = 0; i < 4; i++)
                sVT[nn * 72 + (m0 + qd * 4 + i)] = (__bf16)(acc[i] + bias);
        }
    }
    __syncthreads();

    // ---- P4: |k|^2/2, |q|^2/2; v -> own d_out tile as bf16 [d][64]; zero sKPS ----
    {
        int t = tid >> 3, p = tid & 7;
        bf16x8 kv = *(const bf16x8*)(sK + t * 72 + p * 8);
        bf16x8 qv = *(const bf16x8*)(sQ + t * 72 + p * 8);
        float sk = 0.f, sq = 0.f;
#pragma unroll
        for (int i = 0; i < 8; i++) {
            float a = (float)kv[i]; sk += a * a;
            float c = (float)qv[i]; sq += c * c;
        }
#pragma unroll
        for (int m = 1; m < 8; m <<= 1) { sk += __shfl_xor(sk, m); sq += __shfl_xor(sq, m); }
        if (p == 0) { sXDK[t] = 0.5f * sk; sXDQ[t] = 0.5f * sq; }
        if (tid < 32) sKPS[tid] = 0.f;
        // v park: block-private region (this tile's own output slot, overwritten
        // only by this block's pass2 after it reads). bf16 [d][64], bf16x8 rows.
        __bf16* vg = (__bf16*)(vout + (size_t)(b * Tc + t0) * 64);
        int dd = tid >> 3, tt0 = (tid & 7) * 8;
        *(bf16x8*)(vg + dd * 64 + tt0) = *(const bf16x8*)(sVT + dd * 72 + tt0);
    }
    __syncthreads();

    // ---- P5: kp (waves 0-3 -> sKPT + kps) ; qp (waves 4-7 -> global bf16) ----
    {
        const int wv4 = wv & 3;
        const bool isq = (wv >= 4);
        const __bf16* Aop = isq ? sQ : sK;
        const float* xd = isq ? sXDQ : sXDK;
        __bf16* qg = (__bf16*)(ws + WS_QP) + (size_t)(b * Tc + t0) * 32;
#pragma unroll
        for (int nb = 0; nb < 2; nb++) {
            int m0 = wv4 * 16, n0 = nb * 16;
            f32x4 acc = gemm_tile(Aop + m0 * 72, 72, img + IMG_WF + n0 * 72, 72, 64, r, qd);
            int m = n0 + r;
            if (!isq) {
                float loc = 0.f;
#pragma unroll
                for (int i = 0; i < 4; i++) {
                    int t = m0 + qd * 4 + i;
                    float val = __expf(acc[i] - xd[t]) * 0.17677669529663687f;
                    sKPT[m * 72 + t] = (__bf16)val;
                    loc += val;
                }
                loc += __shfl_xor(loc, 16);
                loc += __shfl_xor(loc, 32);
                if (qd == 0) atomicAdd(&sKPS[m], loc);
            } else {
#pragma unroll
                for (int i = 0; i < 4; i++) {
                    int t = m0 + qd * 4 + i;
                    float val = __expf(acc[i] - xd[t]) * 0.17677669529663687f;
                    qg[t * 32 + m] = (__bf16)val;
                }
            }
        }
    }
    __syncthreads();

    // ---- P6: kptv partials -> global atomics; kps -> global ----
    {
        float* kptv = (float*)(ws + WS_KPTV) + b * 2048;
        int mb = wv & 1, nb = wv >> 1;
        f32x4 acc = gemm_tile(sKPT + mb * 16 * 72, 72, sVT + nb * 16 * 72, 72, 64, r, qd);
#pragma unroll
        for (int i = 0; i < 4; i++) {
            int m = mb * 16 + qd * 4 + i, d = nb * 16 + r;
            atomicAdd(&kptv[d * 32 + m], acc[i]);
        }
        float* kps = (float*)(ws + WS_KPS) + b * 32;
        if (tid < 32) atomicAdd(&kps[tid], sKPS[tid]);
    }
}

// ---------------------------------------------------------------------------
// pass2 LDS (38272 B): byte-identical to R6.
//   region A @0     [10240): sKPTV [64 d][40 m] + sQPL@5120 [64][40] (P0w, P1/P2r)
//                            then sGL@0 [64][72] (P5w, P6r)
//   region B @10240 [9216):  sVLT [64 d][72 t]  (P0w, P3r)
//                            then sYN@10240 [64][72] (P4w, P5r)
//   sYA @19456 [64][72] (P2w, P3r)
//   sYL @28672 [64][72] (P3w, P4r, P6r)
//   sKPS @37888 f32[32]   sDL @38016 f32[64]
__global__ __launch_bounds__(512, 8) void pass2_kernel(
    const float* __restrict__ b2, const float* __restrict__ g2,
    const float* __restrict__ be2, const float* __restrict__ bm1,
    const float* __restrict__ bm2, char* __restrict__ ws,
    float* __restrict__ out) {
    __shared__ __align__(16) char smem[38272];
    __bf16* sKPTV = (__bf16*)(smem);
    __bf16* sQPL  = (__bf16*)(smem + 5120);
    __bf16* sGL   = (__bf16*)(smem);
    __bf16* sVLT  = (__bf16*)(smem + 10240);
    __bf16* sYN   = (__bf16*)(smem + 10240);
    __bf16* sYA   = (__bf16*)(smem + 19456);
    __bf16* sYL   = (__bf16*)(smem + 28672);
    float*  sKPS  = (float*)(smem + 37888);
    float*  sDL   = (float*)(smem + 38016);

    const int tid = threadIdx.x;
    const int wv = tid >> 6, lane = tid & 63, r = lane & 15, qd = lane >> 4;
    const int b = blockIdx.x & 63;
    const int t0 = (blockIdx.x >> 6) << 6;
    const __bf16* img = (const __bf16*)(ws + WS_IMG);

    // ---- P0: load kptv (float4/thread), kps, qp (bf16x8), v (bf16x8) ----
    {
        const f32x4* kp4 = (const f32x4*)((const float*)(ws + WS_KPTV) + b * 2048);
        f32x4 kv = kp4[tid];                       // elements 4*tid .. 4*tid+3
        int d = tid >> 3, m0 = (tid & 7) * 4;      // d = (4*tid)>>5, m0 = (4*tid)&31
        bf16x4 kb;
#pragma unroll
        for (int j = 0; j < 4; j++) kb[j] = (__bf16)kv[j];
        *(bf16x4*)(sKPTV + d * 40 + m0) = kb;
        if (tid < 32) sKPS[tid] = ((const float*)(ws + WS_KPS))[b * 32 + tid];
        if (tid < 256) {
            const bf16x8* qp8 = (const bf16x8*)((const __bf16*)(ws + WS_QP) +
                                                (size_t)(b * Tc + t0) * 32);
            bf16x8 q8 = qp8[tid];                  // elements 8*tid .. 8*tid+7
            int t = tid >> 2, mm = (tid & 3) * 8;  // t = (8*tid)>>5, mm = (8*tid)&31
            *(bf16x8*)(sQPL + t * 40 + mm) = q8;
        }
        const __bf16* vg = (const __bf16*)(out + (size_t)(b * Tc + t0) * 64);
        int dd = tid >> 3, tt0 = (tid & 7) * 8;
        *(bf16x8*)(sVLT + dd * 72 + tt0) = *(const bf16x8*)(vg + dd * 64 + tt0);
    }
    __syncthreads();

    // ---- P1: D = qp . kp_sum + eps ----
    {
        int t = tid >> 3, p = tid & 7;
        float s = 0.f;
#pragma unroll
        for (int j = 0; j < 4; j++) {
            int m = p * 4 + j;
            s += (float)sQPL[t * 40 + m] * sKPS[m];
        }
#pragma unroll
        for (int m = 1; m < 8; m <<= 1) s += __shfl_xor(s, m);
        if (p == 0) sDL[t] = s + 1e-8f;
    }
    __syncthreads();

    // ---- P2: ya = (qp @ kptv^T) / D ----
    for (int id = wv; id < 16; id += 8) {
        int m0 = (id & 3) * 16, n0 = (id >> 2) * 16;
        f32x4 acc = gemm_tile(sQPL + m0 * 40, 40, sKPTV + n0 * 40, 40, 32, r, qd);
        int d = n0 + r;
#pragma unroll
        for (int i = 0; i < 4; i++) {
            int t = m0 + qd * 4 + i;
            sYA[t * 72 + d] = (__bf16)(acc[i] / sDL[t]);
        }
    }
    __syncthreads();

    // ---- P3: y = v + ya @ W_proj2 + b2 ----
    for (int id = wv; id < 16; id += 8) {
        int m0 = (id & 3) * 16, n0 = (id >> 2) * 16;
        f32x4 acc = gemm_tile(sYA + m0 * 72, 72, img + IMG_W2T + n0 * 72, 72, 64, r, qd);
        int d = n0 + r;
        float bias = b2[d];
#pragma unroll
        for (int i = 0; i < 4; i++) {
            int t = m0 + qd * 4 + i;
            sYL[t * 72 + d] = (__bf16)(acc[i] + bias + (float)sVLT[d * 72 + t]);
        }
    }
    __syncthreads();

    // ---- P4: LN2 -> yn (overwrites sVLT region) ----
    {
        int t = tid >> 3, p = tid & 7;
        bf16x8 yv = *(const bf16x8*)(sYL + t * 72 + p * 8);
        float v[8], s1 = 0.f, s2 = 0.f;
#pragma unroll
        for (int i = 0; i < 8; i++) { v[i] = (float)yv[i]; s1 += v[i]; s2 += v[i] * v[i]; }
#pragma unroll
        for (int m = 1; m < 8; m <<= 1) { s1 += __shfl_xor(s1, m); s2 += __shfl_xor(s2, m); }
        float mu = s1 * (1.f / 64.f), var = s2 * (1.f / 64.f) - mu * mu;
        float rstd = rsqrtf(var + 1e-5f);
        bf16x8 o;
#pragma unroll
        for (int i = 0; i < 8; i++) {
            int d = p * 8 + i;
            o[i] = (__bf16)((v[i] - mu) * rstd * g2[d] + be2[d]);
        }
        *(bf16x8*)(sYN + t * 72 + p * 8) = o;
    }
    __syncthreads();

    // ---- P5: gl = gelu(yn @ W_m1 + bm1) (overwrites sKPTV/sQPL region) ----
    for (int id = wv; id < 16; id += 8) {
        int m0 = (id & 3) * 16, n0 = (id >> 2) * 16;
        f32x4 acc = gemm_tile(sYN + m0 * 72, 72, img + IMG_WM1T + n0 * 72, 72, 64, r, qd);
        int d = n0 + r;
        float bias = bm1[d];
#pragma unroll
        for (int i = 0; i < 4; i++) {
            int t = m0 + qd * 4 + i;
            float z = acc[i] + bias;
            sGL[t * 72 + d] = (__bf16)(0.5f * z * (1.f + erff(z * 0.7071067811865475f)));
        }
    }
    __syncthreads();

    // ---- P6: out = y + (gl @ W_m2 + bm2), fp32 store ----
    {
        float* og = out + (size_t)(b * Tc + t0) * 64;
        for (int id = wv; id < 16; id += 8) {
            int m0 = (id & 3) * 16, n0 = (id >> 2) * 16;
            f32x4 acc = gemm_tile(sGL + m0 * 72, 72, img + IMG_WM2T + n0 * 72, 72, 64, r, qd);
            int d = n0 + r;
            float bias = bm2[d];
#pragma unroll
            for (int i = 0; i < 4; i++) {
                int t = m0 + qd * 4 + i;
                og[t * 64 + d] = acc[i] + bias + (float)sYL[t * 72 + d];
            }
        }
    }
}

// ---------------------------------------------------------------------------
extern "C" void kernel_launch(void* const* d_in, const int* in_sizes, int n_in,
                              void* d_out, int out_size, void* d_ws, size_t ws_size,
                              hipStream_t stream) {
    (void)in_sizes; (void)n_in; (void)out_size; (void)ws_size;
    const float* x    = (const float*)d_in[0];
    const float* W1   = (const float*)d_in[1];
    const float* b1   = (const float*)d_in[2];
    const float* Wkqv = (const float*)d_in[3];
    const float* bkqv = (const float*)d_in[4];
    const float* W2   = (const float*)d_in[5];
    const float* b2   = (const float*)d_in[6];
    const float* g1   = (const float*)d_in[7];
    const float* be1  = (const float*)d_in[8];
    const float* g2   = (const float*)d_in[9];
    const float* be2  = (const float*)d_in[10];
    const float* Wm1  = (const float*)d_in[11];
    const float* bm1  = (const float*)d_in[12];
    const float* Wm2  = (const float*)d_in[13];
    const float* bm2  = (const float*)d_in[14];
    const float* wm   = (const float*)d_in[15];
    char* ws = (char*)d_ws;

    hipLaunchKernelGGL(prep_kernel, dim3(128), dim3(256), 0, stream,
                       W1, Wkqv, wm, W2, Wm1, Wm2, ws);
    hipLaunchKernelGGL(pass1_kernel, dim3(3136), dim3(512), 0, stream,
                       x, b1, bkqv, g1, be1, ws, (float*)d_out);
    hipLaunchKernelGGL(pass2_kernel, dim3(3136), dim3(512), 0, stream,
                       b2, g2, be2, bm1, bm2, ws, (float*)d_out);
}

// Round 9
// 291.048 us; speedup vs baseline: 1.7947x; 1.0844x over previous
//
#include <hip/hip_runtime.h>

// ---------------------------------------------------------------------------
// Token performer block, FP32 I/O, internal bf16 MFMA 16x16x32.
// B=64, T=3136, IN=147, D=64, M=32. Tokens tiled 64/block, 512 threads.
// R12: = R11 (verified 315.6us) with the 6.4M device-scope kptv atomicAdds
// replaced by block-private partial stores + a 64-block reduce kernel:
//   - pass1 P6: each block stores its 2048-float kptv partial as float4s
//     into the UPPER HALF of its own out-slot (v-park bf16 occupies float
//     range [0,2048); partial occupies [2048,4096) -- no extra workspace,
//     block-private, no atomics)
//   - reduce_kernel (grid 64 x 512): kptv[b] = sum of 49 partials -> WS_KPTV
//     (same layout pass2 reads; pass2 byte-identical)
//   - kps keeps its tiny atomic path (100K atomics total, negligible)
// Theory: pass1 WRITE_SIZE 138MB = 38.5MB stores + ~100MB atomic fabric
// traffic; atomics are half of pass1's L2<->fabric bytes and a throughput
// serializer. Everything else byte-identical to R11.
// ---------------------------------------------------------------------------

typedef __attribute__((ext_vector_type(8))) __bf16 bf16x8;
typedef __attribute__((ext_vector_type(4))) __bf16 bf16x4;
typedef __attribute__((ext_vector_type(4))) float  f32x4;

#define DEV __device__ __forceinline__

constexpr int Bc = 64, Tc = 3136, INDIM = 147, TM = 64;

// ---- workspace layout (bytes) ----
constexpr size_t WS_QP   = 0;                                   // bf16 B*T*32  [t][m]
constexpr size_t WS_ZERO = WS_QP + (size_t)Bc * Tc * 32 * 2;    // fp32 accumulators
constexpr size_t WS_KPS  = WS_ZERO;                             // fp32 B*32
constexpr size_t WS_KPTV = WS_KPS + (size_t)Bc * 32 * 4;        // fp32 B*64*32 [d][m]
constexpr size_t WS_IMG  = WS_KPTV + (size_t)Bc * 64 * 32 * 4;
constexpr int ZCOUNT = Bc * 32 + Bc * 64 * 32;                  // 133120 floats

// ---- weight image element offsets (bf16 elements) ----
constexpr int IMG_W1T   = 0;      // [64][168]  W_proj1^T, K padded 147->160(+8)
constexpr int IMG_WKQVT = 10752;  // [192][72]  W_kqv^T (k 0..63, q 64..127, v 128..191)
constexpr int IMG_WF    = 24576;  // [32][72]   w [m][d]
constexpr int IMG_W2T   = 26880;  // [64][72]
constexpr int IMG_WM1T  = 31488;  // [64][72]
constexpr int IMG_WM2T  = 36096;  // [64][72]

// wave 16x16 tile GEMM: A rows m-major (k contiguous), B rows n-major (k contiguous).
// out element (m0 + (lane>>4)*4 + i, n0 + (lane&15)) = acc[i]
DEV f32x4 gemm_tile(const __bf16* A, int lda, const __bf16* Bm, int ldb,
                    int K, int r, int qd) {
    f32x4 acc = {0.f, 0.f, 0.f, 0.f};
    const __bf16* ap = A + r * lda + qd * 8;
    const __bf16* bp = Bm + r * ldb + qd * 8;
#pragma unroll
    for (int k = 0; k < 160; k += 32) {
        if (k >= K) break;
        bf16x8 av = *(const bf16x8*)(ap + k);
        bf16x8 bv = *(const bf16x8*)(bp + k);
        acc = __builtin_amdgcn_mfma_f32_16x16x32_bf16(av, bv, acc, 0, 0, 0);
    }
    return acc;
}

// ---------------------------------------------------------------------------
__global__ void prep_kernel(const float* __restrict__ W1, const float* __restrict__ Wkqv,
                            const float* __restrict__ wm, const float* __restrict__ W2,
                            const float* __restrict__ Wm1, const float* __restrict__ Wm2,
                            char* __restrict__ ws) {
    const int tid = blockIdx.x * blockDim.x + threadIdx.x;
    const int n = gridDim.x * blockDim.x;
    float* z = (float*)(ws + WS_ZERO);
    for (int i = tid; i < ZCOUNT; i += n) z[i] = 0.f;
    __bf16* img = (__bf16*)(ws + WS_IMG);
    for (int i = tid; i < 64 * 168; i += n) {   // W1T [d][k]
        int d = i / 168, k = i - d * 168;
        img[IMG_W1T + i] = (k < 147) ? (__bf16)W1[k * 64 + d] : (__bf16)0.f;
    }
    for (int i = tid; i < 192 * 72; i += n) {   // WkqvT [c][k]
        int c = i / 72, k = i - c * 72;
        img[IMG_WKQVT + i] = (k < 64) ? (__bf16)Wkqv[k * 192 + c] : (__bf16)0.f;
    }
    for (int i = tid; i < 32 * 72; i += n) {    // wF [m][d]
        int m = i / 72, k = i - m * 72;
        img[IMG_WF + i] = (k < 64) ? (__bf16)wm[m * 64 + k] : (__bf16)0.f;
    }
    for (int i = tid; i < 64 * 72; i += n) {
        int c = i / 72, k = i - c * 72;
        img[IMG_W2T + i] = (k < 64) ? (__bf16)W2[k * 64 + c] : (__bf16)0.f;
    }
    for (int i = tid; i < 64 * 72; i += n) {
        int c = i / 72, k = i - c * 72;
        img[IMG_WM1T + i] = (k < 64) ? (__bf16)Wm1[k * 64 + c] : (__bf16)0.f;
    }
    for (int i = tid; i < 64 * 72; i += n) {
        int c = i / 72, k = i - c * 72;
        img[IMG_WM2T + i] = (k < 64) ? (__bf16)Wm2[k * 64 + c] : (__bf16)0.f;
    }
}

// ---------------------------------------------------------------------------
// pass1 LDS (38912 B): layout identical to R11.
__global__ __launch_bounds__(512, 8) void pass1_kernel(
    const float* __restrict__ x, const float* __restrict__ b1,
    const float* __restrict__ bkqv, const float* __restrict__ g1,
    const float* __restrict__ be1, char* __restrict__ ws,
    float* __restrict__ vout) {
    __shared__ __align__(16) char smem[38912];
    __bf16* sXT  = (__bf16*)(smem);
    __bf16* sK   = (__bf16*)(smem);
    __bf16* sQ   = (__bf16*)(smem + 9216);
    float*  sXDK = (float*)(smem + 18432);
    float*  sXDQ = (float*)(smem + 18688);
    float*  sKPS = (float*)(smem + 18944);
    __bf16* sH   = (__bf16*)(smem + 20480);
    __bf16* sKPT = (__bf16*)(smem + 20480);
    __bf16* sVT  = (__bf16*)(smem + 29696);

    const int tid = threadIdx.x;
    const int wv = tid >> 6, lane = tid & 63, r = lane & 15, qd = lane >> 4;
    const int b = blockIdx.x & 63;
    const int t0 = (blockIdx.x >> 6) << 6;
    const __bf16* img = (const __bf16*)(ws + WS_IMG);

    // ---- P0: stage x tile fp32->bf16, float4 loads (stride 160 in LDS) ----
    {
        const float* xrow = x + (size_t)(b * Tc + t0) * INDIM;
        const f32x4* xp4 = (const f32x4*)xrow;                  // 2352 float4s
        for (int i4 = tid; i4 < 2352; i4 += 512) {
            f32x4 xv = xp4[i4];
            int g = i4 << 2;
            int t = g / 147;
            int k = g - t * 147;
#pragma unroll
            for (int j = 0; j < 4; j++) {
                sXT[t * 160 + k] = (__bf16)xv[j];
                k++;
                if (k == 147) { k = 0; t++; }
            }
        }
        for (int i = tid; i < TM * 13; i += 512) {
            int t = i / 13, k = 147 + (i - t * 13);
            sXT[t * 160 + k] = (__bf16)0.f;
        }
    }
    __syncthreads();

    // ---- P1: h = x @ W1 + b1 (A lda=160; B image stride 168 unchanged) ----
    for (int id = wv; id < 16; id += 8) {
        int m0 = (id & 3) * 16, n0 = (id >> 2) * 16;
        f32x4 acc = gemm_tile(sXT + m0 * 160, 160, img + IMG_W1T + n0 * 168, 168, 160, r, qd);
        int d = n0 + r;
        float bias = b1[d];
#pragma unroll
        for (int i = 0; i < 4; i++)
            sH[(m0 + qd * 4 + i) * 72 + d] = (__bf16)(acc[i] + bias);
    }
    __syncthreads();

    // ---- P2: LN1 in place ----
    {
        int t = tid >> 3, p = tid & 7;
        __bf16* hp = sH + t * 72 + p * 8;
        bf16x8 hv = *(const bf16x8*)hp;
        float v[8], s1 = 0.f, s2 = 0.f;
#pragma unroll
        for (int i = 0; i < 8; i++) { v[i] = (float)hv[i]; s1 += v[i]; s2 += v[i] * v[i]; }
#pragma unroll
        for (int m = 1; m < 8; m <<= 1) { s1 += __shfl_xor(s1, m); s2 += __shfl_xor(s2, m); }
        float mu = s1 * (1.f / 64.f), var = s2 * (1.f / 64.f) - mu * mu;
        float rstd = rsqrtf(var + 1e-5f);
        bf16x8 o;
#pragma unroll
        for (int i = 0; i < 8; i++) {
            int d = p * 8 + i;
            o[i] = (__bf16)((v[i] - mu) * rstd * g1[d] + be1[d]);
        }
        *(bf16x8*)hp = o;
    }
    __syncthreads();

    // ---- P3: k, q, v = hn @ Wk/Wq/Wv + bias (48 tiles; sK/sQ overwrite sXT) ----
    for (int id = wv; id < 48; id += 8) {
        int which = id >> 4, tl = id & 15;
        int m0 = (tl & 3) * 16, n0 = (tl >> 2) * 16;
        const __bf16* Bm = img + IMG_WKQVT + which * 64 * 72 + n0 * 72;
        f32x4 acc = gemm_tile(sH + m0 * 72, 72, Bm, 72, 64, r, qd);
        int nn = n0 + r;
        float bias = bkqv[which * 64 + nn];
        if (which == 0) {
#pragma unroll
            for (int i = 0; i < 4; i++)
                sK[(m0 + qd * 4 + i) * 72 + nn] = (__bf16)(acc[i] + bias);
        } else if (which == 1) {
#pragma unroll
            for (int i = 0; i < 4; i++)
                sQ[(m0 + qd * 4 + i) * 72 + nn] = (__bf16)(acc[i] + bias);
        } else {
#pragma unroll
            for (int i = 0; i < 4; i++)
                sVT[nn * 72 + (m0 + qd * 4 + i)] = (__bf16)(acc[i] + bias);
        }
    }
    __syncthreads();

    // ---- P4: |k|^2/2, |q|^2/2; v -> own d_out tile as bf16 [d][64]; zero sKPS ----
    {
        int t = tid >> 3, p = tid & 7;
        bf16x8 kv = *(const bf16x8*)(sK + t * 72 + p * 8);
        bf16x8 qv = *(const bf16x8*)(sQ + t * 72 + p * 8);
        float sk = 0.f, sq = 0.f;
#pragma unroll
        for (int i = 0; i < 8; i++) {
            float a = (float)kv[i]; sk += a * a;
            float c = (float)qv[i]; sq += c * c;
        }
#pragma unroll
        for (int m = 1; m < 8; m <<= 1) { sk += __shfl_xor(sk, m); sq += __shfl_xor(sq, m); }
        if (p == 0) { sXDK[t] = 0.5f * sk; sXDQ[t] = 0.5f * sq; }
        if (tid < 32) sKPS[tid] = 0.f;
        // v park: lower half (floats [0,2048)) of this tile's own out slot.
        __bf16* vg = (__bf16*)(vout + (size_t)(b * Tc + t0) * 64);
        int dd = tid >> 3, tt0 = (tid & 7) * 8;
        *(bf16x8*)(vg + dd * 64 + tt0) = *(const bf16x8*)(sVT + dd * 72 + tt0);
    }
    __syncthreads();

    // ---- P5: kp (waves 0-3 -> sKPT + kps) ; qp (waves 4-7 -> global bf16) ----
    {
        const int wv4 = wv & 3;
        const bool isq = (wv >= 4);
        const __bf16* Aop = isq ? sQ : sK;
        const float* xd = isq ? sXDQ : sXDK;
        __bf16* qg = (__bf16*)(ws + WS_QP) + (size_t)(b * Tc + t0) * 32;
#pragma unroll
        for (int nb = 0; nb < 2; nb++) {
            int m0 = wv4 * 16, n0 = nb * 16;
            f32x4 acc = gemm_tile(Aop + m0 * 72, 72, img + IMG_WF + n0 * 72, 72, 64, r, qd);
            int m = n0 + r;
            if (!isq) {
                float loc = 0.f;
#pragma unroll
                for (int i = 0; i < 4; i++) {
                    int t = m0 + qd * 4 + i;
                    float val = __expf(acc[i] - xd[t]) * 0.17677669529663687f;
                    sKPT[m * 72 + t] = (__bf16)val;
                    loc += val;
                }
                loc += __shfl_xor(loc, 16);
                loc += __shfl_xor(loc, 32);
                if (qd == 0) atomicAdd(&sKPS[m], loc);
            } else {
#pragma unroll
                for (int i = 0; i < 4; i++) {
                    int t = m0 + qd * 4 + i;
                    float val = __expf(acc[i] - xd[t]) * 0.17677669529663687f;
                    qg[t * 32 + m] = (__bf16)val;
                }
            }
        }
    }
    __syncthreads();

    // ---- P6: kptv partial -> PLAIN float4 store into upper half (floats
    //      [2048,4096)) of this tile's own out slot; kps -> tiny atomics ----
    {
        int mb = wv & 1, nb = wv >> 1;
        f32x4 acc = gemm_tile(sKPT + mb * 16 * 72, 72, sVT + nb * 16 * 72, 72, 64, r, qd);
        // element (m = mb*16+qd*4+i, d = nb*16+r); i=0..3 consecutive -> one float4
        float* part = vout + (size_t)(b * Tc + t0) * 64 + 2048;
        int m = mb * 16 + qd * 4, d = nb * 16 + r;
        *(f32x4*)(part + d * 32 + m) = acc;
        float* kps = (float*)(ws + WS_KPS) + b * 32;
        if (tid < 32) atomicAdd(&kps[tid], sKPS[tid]);
    }
}

// ---------------------------------------------------------------------------
// reduce: kptv[b][e] = sum over 49 tiles of the per-tile partials parked in
// the upper halves of batch b's out slots. Grid 64 x 512; thread = one float4.
__global__ __launch_bounds__(512) void reduce_kernel(
    const float* __restrict__ outbuf, char* __restrict__ ws) {
    const int b = blockIdx.x;
    const int e = threadIdx.x * 4;
    const float* base = outbuf + (size_t)b * Tc * 64 + 2048 + e;
    f32x4 s = {0.f, 0.f, 0.f, 0.f};
#pragma unroll 7
    for (int j = 0; j < 49; j++) {
        f32x4 v = *(const f32x4*)(base + (size_t)j * 4096);
        s[0] += v[0]; s[1] += v[1]; s[2] += v[2]; s[3] += v[3];
    }
    *(f32x4*)((float*)(ws + WS_KPTV) + b * 2048 + e) = s;
}

// ---------------------------------------------------------------------------
// pass2 LDS (38272 B): byte-identical to R6/R11.
__global__ __launch_bounds__(512, 8) void pass2_kernel(
    const float* __restrict__ b2, const float* __restrict__ g2,
    const float* __restrict__ be2, const float* __restrict__ bm1,
    const float* __restrict__ bm2, char* __restrict__ ws,
    float* __restrict__ out) {
    __shared__ __align__(16) char smem[38272];
    __bf16* sKPTV = (__bf16*)(smem);
    __bf16* sQPL  = (__bf16*)(smem + 5120);
    __bf16* sGL   = (__bf16*)(smem);
    __bf16* sVLT  = (__bf16*)(smem + 10240);
    __bf16* sYN   = (__bf16*)(smem + 10240);
    __bf16* sYA   = (__bf16*)(smem + 19456);
    __bf16* sYL   = (__bf16*)(smem + 28672);
    float*  sKPS  = (float*)(smem + 37888);
    float*  sDL   = (float*)(smem + 38016);

    const int tid = threadIdx.x;
    const int wv = tid >> 6, lane = tid & 63, r = lane & 15, qd = lane >> 4;
    const int b = blockIdx.x & 63;
    const int t0 = (blockIdx.x >> 6) << 6;
    const __bf16* img = (const __bf16*)(ws + WS_IMG);

    // ---- P0: load kptv (float4/thread), kps, qp (bf16x8), v (bf16x8) ----
    {
        const f32x4* kp4 = (const f32x4*)((const float*)(ws + WS_KPTV) + b * 2048);
        f32x4 kv = kp4[tid];                       // elements 4*tid .. 4*tid+3
        int d = tid >> 3, m0 = (tid & 7) * 4;      // d = (4*tid)>>5, m0 = (4*tid)&31
        bf16x4 kb;
#pragma unroll
        for (int j = 0; j < 4; j++) kb[j] = (__bf16)kv[j];
        *(bf16x4*)(sKPTV + d * 40 + m0) = kb;
        if (tid < 32) sKPS[tid] = ((const float*)(ws + WS_KPS))[b * 32 + tid];
        if (tid < 256) {
            const bf16x8* qp8 = (const bf16x8*)((const __bf16*)(ws + WS_QP) +
                                                (size_t)(b * Tc + t0) * 32);
            bf16x8 q8 = qp8[tid];                  // elements 8*tid .. 8*tid+7
            int t = tid >> 2, mm = (tid & 3) * 8;  // t = (8*tid)>>5, mm = (8*tid)&31
            *(bf16x8*)(sQPL + t * 40 + mm) = q8;
        }
        const __bf16* vg = (const __bf16*)(out + (size_t)(b * Tc + t0) * 64);
        int dd = tid >> 3, tt0 = (tid & 7) * 8;
        *(bf16x8*)(sVLT + dd * 72 + tt0) = *(const bf16x8*)(vg + dd * 64 + tt0);
    }
    __syncthreads();

    // ---- P1: D = qp . kp_sum + eps ----
    {
        int t = tid >> 3, p = tid & 7;
        float s = 0.f;
#pragma unroll
        for (int j = 0; j < 4; j++) {
            int m = p * 4 + j;
            s += (float)sQPL[t * 40 + m] * sKPS[m];
        }
#pragma unroll
        for (int m = 1; m < 8; m <<= 1) s += __shfl_xor(s, m);
        if (p == 0) sDL[t] = s + 1e-8f;
    }
    __syncthreads();

    // ---- P2: ya = (qp @ kptv^T) / D ----
    for (int id = wv; id < 16; id += 8) {
        int m0 = (id & 3) * 16, n0 = (id >> 2) * 16;
        f32x4 acc = gemm_tile(sQPL + m0 * 40, 40, sKPTV + n0 * 40, 40, 32, r, qd);
        int d = n0 + r;
#pragma unroll
        for (int i = 0; i < 4; i++) {
            int t = m0 + qd * 4 + i;
            sYA[t * 72 + d] = (__bf16)(acc[i] / sDL[t]);
        }
    }
    __syncthreads();

    // ---- P3: y = v + ya @ W_proj2 + b2 ----
    for (int id = wv; id < 16; id += 8) {
        int m0 = (id & 3) * 16, n0 = (id >> 2) * 16;
        f32x4 acc = gemm_tile(sYA + m0 * 72, 72, img + IMG_W2T + n0 * 72, 72, 64, r, qd);
        int d = n0 + r;
        float bias = b2[d];
#pragma unroll
        for (int i = 0; i < 4; i++) {
            int t = m0 + qd * 4 + i;
            sYL[t * 72 + d] = (__bf16)(acc[i] + bias + (float)sVLT[d * 72 + t]);
        }
    }
    __syncthreads();

    // ---- P4: LN2 -> yn (overwrites sVLT region) ----
    {
        int t = tid >> 3, p = tid & 7;
        bf16x8 yv = *(const bf16x8*)(sYL + t * 72 + p * 8);
        float v[8], s1 = 0.f, s2 = 0.f;
#pragma unroll
        for (int i = 0; i < 8; i++) { v[i] = (float)yv[i]; s1 += v[i]; s2 += v[i] * v[i]; }
#pragma unroll
        for (int m = 1; m < 8; m <<= 1) { s1 += __shfl_xor(s1, m); s2 += __shfl_xor(s2, m); }
        float mu = s1 * (1.f / 64.f), var = s2 * (1.f / 64.f) - mu * mu;
        float rstd = rsqrtf(var + 1e-5f);
        bf16x8 o;
#pragma unroll
        for (int i = 0; i < 8; i++) {
            int d = p * 8 + i;
            o[i] = (__bf16)((v[i] - mu) * rstd * g2[d] + be2[d]);
        }
        *(bf16x8*)(sYN + t * 72 + p * 8) = o;
    }
    __syncthreads();

    // ---- P5: gl = gelu(yn @ W_m1 + bm1) (overwrites sKPTV/sQPL region) ----
    for (int id = wv; id < 16; id += 8) {
        int m0 = (id & 3) * 16, n0 = (id >> 2) * 16;
        f32x4 acc = gemm_tile(sYN + m0 * 72, 72, img + IMG_WM1T + n0 * 72, 72, 64, r, qd);
        int d = n0 + r;
        float bias = bm1[d];
#pragma unroll
        for (int i = 0; i < 4; i++) {
            int t = m0 + qd * 4 + i;
            float z = acc[i] + bias;
            sGL[t * 72 + d] = (__bf16)(0.5f * z * (1.f + erff(z * 0.7071067811865475f)));
        }
    }
    __syncthreads();

    // ---- P6: out = y + (gl @ W_m2 + bm2), fp32 store ----
    {
        float* og = out + (size_t)(b * Tc + t0) * 64;
        for (int id = wv; id < 16; id += 8) {
            int m0 = (id & 3) * 16, n0 = (id >> 2) * 16;
            f32x4 acc = gemm_tile(sGL + m0 * 72, 72, img + IMG_WM2T + n0 * 72, 72, 64, r, qd);
            int d = n0 + r;
            float bias = bm2[d];
#pragma unroll
            for (int i = 0; i < 4; i++) {
                int t = m0 + qd * 4 + i;
                og[t * 64 + d] = acc[i] + bias + (float)sYL[t * 72 + d];
            }
        }
    }
}

// ---------------------------------------------------------------------------
extern "C" void kernel_launch(void* const* d_in, const int* in_sizes, int n_in,
                              void* d_out, int out_size, void* d_ws, size_t ws_size,
                              hipStream_t stream) {
    (void)in_sizes; (void)n_in; (void)out_size; (void)ws_size;
    const float* x    = (const float*)d_in[0];
    const float* W1   = (const float*)d_in[1];
    const float* b1   = (const float*)d_in[2];
    const float* Wkqv = (const float*)d_in[3];
    const float* bkqv = (const float*)d_in[4];
    const float* W2   = (const float*)d_in[5];
    const float* b2   = (const float*)d_in[6];
    const float* g1   = (const float*)d_in[7];
    const float* be1  = (const float*)d_in[8];
    const float* g2   = (const float*)d_in[9];
    const float* be2  = (const float*)d_in[10];
    const float* Wm1  = (const float*)d_in[11];
    const float* bm1  = (const float*)d_in[12];
    const float* Wm2  = (const float*)d_in[13];
    const float* bm2  = (const float*)d_in[14];
    const float* wm   = (const float*)d_in[15];
    char* ws = (char*)d_ws;

    hipLaunchKernelGGL(prep_kernel, dim3(128), dim3(256), 0, stream,
                       W1, Wkqv, wm, W2, Wm1, Wm2, ws);
    hipLaunchKernelGGL(pass1_kernel, dim3(3136), dim3(512), 0, stream,
                       x, b1, bkqv, g1, be1, ws, (float*)d_out);
    hipLaunchKernelGGL(reduce_kernel, dim3(64), dim3(512), 0, stream,
                       (const float*)d_out, ws);
    hipLaunchKernelGGL(pass2_kernel, dim3(3136), dim3(512), 0, stream,
                       b2, g2, be2, bm1, bm2, ws, (float*)d_out);
}